// Round 2
// baseline (1915.134 us; speedup 1.0000x reference)
//
#include <hip/hip_runtime.h>
#include <math.h>

// ---------------- problem constants ----------------
#define TLEN   64000
#define ECH    256
#define DCH    512
#define NBLK   2
#define NLAY   6
#define FKC    20
#define STRIDE_ 10
#define TC     6403            // encoder output length
#define NS     12928           // padded column stride = 101*128
#define NTILE  101             // NS / 128
#define EPSV   1e-5f

// =====================================================================
// Encoder: enc[b,e,tc] = sum_k x[b, tc*10 + k - 20] * ew[e,k] + eb[e]
// Writes both enc and H (initial hidden state). Zero for padded columns.
// =====================================================================
__global__ __launch_bounds__(256)
void encoder_k(const float* __restrict__ x, const float* __restrict__ ew,
               const float* __restrict__ eb, float* __restrict__ enc,
               float* __restrict__ H)
{
    int n = blockIdx.x * 256 + threadIdx.x;
    int e = blockIdx.y;
    if (n >= NS) return;
    int b  = (n >= TC) ? 1 : 0;
    int tc = n - b * TC;
    float acc = 0.f;
    if (tc < TC) {
        acc = eb[e];
        const float* xb = x + b * TLEN;
        int base = tc * STRIDE_ - FKC;
        #pragma unroll
        for (int k = 0; k < FKC; ++k) {
            int idx = base + k;
            if (idx >= 0 && idx < TLEN) acc += xb[idx] * ew[e * FKC + k];
        }
    }
    enc[(size_t)e * NS + n] = acc;
    H[(size_t)e * NS + n]   = acc;
}

// =====================================================================
// Tiled fp32 GEMM: Out[M][NS] = W[M][KD] * Hin[KD][NS]  (+ fused epilogue)
// EPI 0: +bias, PReLU(alpha), BN(gamma,beta,mean,var)        (conv1)
// EPI 1: +bias                                               (conv2)
// EPI 2: +bias +Resid                                        (conv2, last layer)
// BM=128 BN=128 BK=16, 256 threads, 8x8 micro-tile (split 4+4 / 4+4).
// =====================================================================
template<int KD, int EPI>
__global__ __launch_bounds__(256)
void gemm_k(const float* __restrict__ W, const float* __restrict__ Hin,
            float* __restrict__ Out, const float* __restrict__ bias,
            const float* __restrict__ alpha, const float* __restrict__ gamma,
            const float* __restrict__ beta,  const float* __restrict__ mean,
            const float* __restrict__ var,   const float* __restrict__ Resid)
{
    __shared__ float At[16][128];   // [k][m]
    __shared__ float Bt[16][128];   // [k][n]

    const int tid = threadIdx.x;
    const int tm  = tid & 15;        // 16 m-groups
    const int tn  = tid >> 4;        // 16 n-groups
    const int mb  = blockIdx.y * 128;
    const int nb  = blockIdx.x * 128;

    const int arow = tid >> 2;          // 0..63
    const int akc  = (tid & 3) << 2;    // 0,4,8,12

    float acc[8][8];
    #pragma unroll
    for (int i = 0; i < 8; ++i)
        #pragma unroll
        for (int j = 0; j < 8; ++j) acc[i][j] = 0.f;

    for (int kb = 0; kb < KD; kb += 16) {
        // global loads
        float4 av0 = *reinterpret_cast<const float4*>(&W[(size_t)(mb + arow) * KD + kb + akc]);
        float4 av1 = *reinterpret_cast<const float4*>(&W[(size_t)(mb + arow + 64) * KD + kb + akc]);
        int lin0 = tid, lin1 = tid + 256;
        float4 bv0 = *reinterpret_cast<const float4*>(
            &Hin[(size_t)(kb + (lin0 >> 5)) * NS + nb + ((lin0 & 31) << 2)]);
        float4 bv1 = *reinterpret_cast<const float4*>(
            &Hin[(size_t)(kb + (lin1 >> 5)) * NS + nb + ((lin1 & 31) << 2)]);

        __syncthreads();   // previous iteration's reads complete
        At[akc + 0][arow] = av0.x;
        At[akc + 1][arow] = av0.y;
        At[akc + 2][arow] = av0.z;
        At[akc + 3][arow] = av0.w;
        At[akc + 0][arow + 64] = av1.x;
        At[akc + 1][arow + 64] = av1.y;
        At[akc + 2][arow + 64] = av1.z;
        At[akc + 3][arow + 64] = av1.w;
        *reinterpret_cast<float4*>(&Bt[lin0 >> 5][(lin0 & 31) << 2]) = bv0;
        *reinterpret_cast<float4*>(&Bt[lin1 >> 5][(lin1 & 31) << 2]) = bv1;
        __syncthreads();   // writes visible

        #pragma unroll
        for (int kk = 0; kk < 16; ++kk) {
            float4 a0 = *reinterpret_cast<const float4*>(&At[kk][tm << 2]);
            float4 a1 = *reinterpret_cast<const float4*>(&At[kk][64 + (tm << 2)]);
            float4 b0 = *reinterpret_cast<const float4*>(&Bt[kk][tn << 2]);
            float4 b1 = *reinterpret_cast<const float4*>(&Bt[kk][64 + (tn << 2)]);
            float am[8] = {a0.x, a0.y, a0.z, a0.w, a1.x, a1.y, a1.z, a1.w};
            float bn_[8] = {b0.x, b0.y, b0.z, b0.w, b1.x, b1.y, b1.z, b1.w};
            #pragma unroll
            for (int i = 0; i < 8; ++i)
                #pragma unroll
                for (int j = 0; j < 8; ++j)
                    acc[i][j] = fmaf(am[i], bn_[j], acc[i][j]);
        }
    }

    // epilogue: 8 rows (2 groups of 4), 8 cols (2 groups of 4)
    #pragma unroll
    for (int i = 0; i < 8; ++i) {
        int r = mb + ((i < 4) ? ((tm << 2) + i) : (64 + (tm << 2) + i - 4));
        float* orow = Out + (size_t)r * NS + nb;
        float bz = bias[r];
        float al = 0.f, sc = 0.f, mn = 0.f, bt = 0.f;
        if (EPI == 0) {
            al = alpha[0];
            sc = gamma[r] / sqrtf(var[r] + EPSV);
            mn = mean[r];
            bt = beta[r];
        }
        float v[8];
        #pragma unroll
        for (int j = 0; j < 8; ++j) {
            float y = acc[i][j] + bz;
            if (EPI == 0) {
                y = (y > 0.f) ? y : al * y;
                y = (y - mn) * sc + bt;
            }
            v[j] = y;
        }
        if (EPI == 2) {
            const float* rrow = Resid + (size_t)r * NS + nb;
            #pragma unroll
            for (int j = 0; j < 4; ++j) v[j]     += rrow[(tn << 2) + j];
            #pragma unroll
            for (int j = 0; j < 4; ++j) v[4 + j] += rrow[64 + (tn << 2) + j];
        }
        float4 s0 = {v[0], v[1], v[2], v[3]};
        float4 s1 = {v[4], v[5], v[6], v[7]};
        *reinterpret_cast<float4*>(&orow[tn << 2])        = s0;
        *reinterpret_cast<float4*>(&orow[64 + (tn << 2)]) = s1;
    }
}

// =====================================================================
// Depthwise K=3 dilated conv + bias + PReLU + BN, per (d, n)
// =====================================================================
__global__ __launch_bounds__(256)
void dw_k(const float* __restrict__ P, const float* __restrict__ wd,
          const float* __restrict__ bd, const float* __restrict__ a2,
          const float* __restrict__ g2, const float* __restrict__ be2,
          const float* __restrict__ m2, const float* __restrict__ v2,
          float* __restrict__ Q, int dil)
{
    int n = blockIdx.x * 256 + threadIdx.x;
    int d = blockIdx.y;
    if (n >= NS) return;
    int b = (n >= TC) ? 1 : 0;
    int t = n - b * TC;
    const float* row = P + (size_t)d * NS + b * TC;

    float w0 = wd[d * 3 + 0], w1 = wd[d * 3 + 1], w2v = wd[d * 3 + 2];
    float acc = w1 * row[t];
    if (t - dil >= 0) acc += w0 * row[t - dil];
    if (t + dil < TC) acc += w2v * row[t + dil];
    acc += bd[d];
    float al = a2[0];
    acc = (acc > 0.f) ? acc : al * acc;
    float sc = g2[d] / sqrtf(v2[d] + EPSV);
    acc = (acc - m2[d]) * sc + be2[d];
    Q[(size_t)d * NS + n] = acc;
}

// =====================================================================
// mask + apply: masked = enc * sigmoid(H)
// =====================================================================
__global__ __launch_bounds__(256)
void mask_k(const float* __restrict__ enc, const float* __restrict__ Hf,
            float* __restrict__ masked)
{
    size_t i = (size_t)blockIdx.x * 256 + threadIdx.x;
    if (i >= (size_t)ECH * NS) return;
    float hv = Hf[i];
    float s  = 1.f / (1.f + expf(-hv));
    masked[i] = enc[i] * s;
}

// =====================================================================
// Decoder (ConvTranspose1d E->1, K=20, stride=10, slice [FK:T+FK]).
// out[t0*10 + j] = db + sum_e m0*dw[e][j] + m1*dw[e][j+10],
//   m0 = masked[e][tc0], m1 = masked[e][tc0-1], tc0 = t0+2.
// =====================================================================
__global__ __launch_bounds__(256)
void decoder_k(const float* __restrict__ masked, const float* __restrict__ dw,
               const float* __restrict__ db, float* __restrict__ out)
{
    int t0 = blockIdx.x * 256 + threadIdx.x;   // 0..6399
    int b  = blockIdx.y;
    if (t0 >= TLEN / STRIDE_) return;
    int tc0 = t0 + 2;
    float acc[10];
    #pragma unroll
    for (int j = 0; j < 10; ++j) acc[j] = 0.f;

    const float* mcol = masked + (size_t)b * TC + tc0;
    for (int e = 0; e < ECH; ++e) {
        float m0 = mcol[(size_t)e * NS];
        float m1 = mcol[(size_t)e * NS - 1];
        const float* wrow = dw + e * FKC;
        #pragma unroll
        for (int j = 0; j < 10; ++j)
            acc[j] = fmaf(m0, wrow[j], fmaf(m1, wrow[j + 10], acc[j]));
    }
    float bz = db[0];
    float* orow = out + (size_t)b * TLEN + t0 * 10;
    #pragma unroll
    for (int j = 0; j < 10; ++j) orow[j] = acc[j] + bz;
}

// =====================================================================
extern "C" void kernel_launch(void* const* d_in, const int* in_sizes, int n_in,
                              void* d_out, int out_size, void* d_ws, size_t ws_size,
                              hipStream_t stream)
{
    const float* x     = (const float*)d_in[0];
    const float* enc_w = (const float*)d_in[1];
    const float* enc_b = (const float*)d_in[2];
    const float* w1    = (const float*)d_in[3];
    const float* b1    = (const float*)d_in[4];
    const float* a1    = (const float*)d_in[5];
    const float* g1    = (const float*)d_in[6];
    const float* be1   = (const float*)d_in[7];
    const float* m1    = (const float*)d_in[8];
    const float* v1    = (const float*)d_in[9];
    const float* wd    = (const float*)d_in[10];
    const float* bd    = (const float*)d_in[11];
    const float* a2    = (const float*)d_in[12];
    const float* g2    = (const float*)d_in[13];
    const float* be2   = (const float*)d_in[14];
    const float* m2    = (const float*)d_in[15];
    const float* v2    = (const float*)d_in[16];
    const float* w2    = (const float*)d_in[17];
    const float* b2    = (const float*)d_in[18];
    const float* dec_w = (const float*)d_in[19];
    const float* dec_b = (const float*)d_in[20];
    float* out = (float*)d_out;

    float* ws  = (float*)d_ws;
    float* H   = ws;                           // [ECH][NS]
    float* enc = H   + (size_t)ECH * NS;       // [ECH][NS]
    float* R   = enc + (size_t)ECH * NS;       // [ECH][NS]
    float* P   = R   + (size_t)ECH * NS;       // [DCH][NS]
    float* Q   = P   + (size_t)DCH * NS;       // [DCH][NS]

    dim3 blk(256);
    dim3 gEnc((NS + 255) / 256, ECH);
    encoder_k<<<gEnc, blk, 0, stream>>>(x, enc_w, enc_b, enc, H);

    for (int bI = 0; bI < NBLK; ++bI) {
        hipMemcpyAsync(R, H, sizeof(float) * (size_t)ECH * NS,
                       hipMemcpyDeviceToDevice, stream);
        for (int i = 0; i < NLAY; ++i) {
            int li  = bI * NLAY + i;
            int dil = 1 << i;
            // conv1: E->D, fused bias+PReLU+BN
            gemm_k<ECH, 0><<<dim3(NTILE, DCH / 128), blk, 0, stream>>>(
                w1 + (size_t)li * DCH * ECH, H, P,
                b1 + (size_t)li * DCH, a1 + li,
                g1 + (size_t)li * DCH, be1 + (size_t)li * DCH,
                m1 + (size_t)li * DCH, v1 + (size_t)li * DCH, nullptr);
            // depthwise + bias + PReLU + BN
            dim3 gDw((NS + 255) / 256, DCH);
            dw_k<<<gDw, blk, 0, stream>>>(
                P, wd + (size_t)li * DCH * 3, bd + (size_t)li * DCH, a2 + li,
                g2 + (size_t)li * DCH, be2 + (size_t)li * DCH,
                m2 + (size_t)li * DCH, v2 + (size_t)li * DCH, Q, dil);
            // conv2: D->E (+ residual on last layer of block)
            if (i == NLAY - 1) {
                gemm_k<DCH, 2><<<dim3(NTILE, ECH / 128), blk, 0, stream>>>(
                    w2 + (size_t)li * ECH * DCH, Q, H,
                    b2 + (size_t)li * ECH, nullptr, nullptr, nullptr, nullptr,
                    nullptr, R);
            } else {
                gemm_k<DCH, 1><<<dim3(NTILE, ECH / 128), blk, 0, stream>>>(
                    w2 + (size_t)li * ECH * DCH, Q, H,
                    b2 + (size_t)li * ECH, nullptr, nullptr, nullptr, nullptr,
                    nullptr, nullptr);
            }
        }
    }

    // mask + apply (masked into P)
    size_t totE = (size_t)ECH * NS;
    mask_k<<<dim3((unsigned)((totE + 255) / 256)), blk, 0, stream>>>(enc, H, P);

    // decoder
    decoder_k<<<dim3(TLEN / STRIDE_ / 256 + ((TLEN / STRIDE_ % 256) ? 1 : 0), NBLK),
                blk, 0, stream>>>(P, dec_w, dec_b, out);
}

// Round 4
// 1024.159 us; speedup vs baseline: 1.8700x; 1.8700x over previous
//
#include <hip/hip_runtime.h>
#include <math.h>

// ---------------- problem constants ----------------
#define TLEN   64000
#define ECH    256
#define DCH    512
#define NBLK   2
#define NLAY   6
#define FKC    20
#define STRIDE_ 10
#define TC     6403            // encoder output length
#define NS     12928           // padded column stride = 101*128
#define NTILE  101             // NS / 128
#define EPSV   1e-5f

typedef __attribute__((ext_vector_type(8))) short          s8v;
typedef __attribute__((ext_vector_type(4))) float          f4v;
typedef __attribute__((ext_vector_type(4))) unsigned short u4v;

__device__ __forceinline__ unsigned short f2bf(float f) {
    union { float f; unsigned u; } v; v.f = f;
    unsigned r = v.u + 0x7FFFu + ((v.u >> 16) & 1u);   // RNE
    return (unsigned short)(r >> 16);
}

// =====================================================================
// Encoder (round-2 verbatim, known-correct)
// =====================================================================
__global__ __launch_bounds__(256)
void encoder_k(const float* __restrict__ x, const float* __restrict__ ew,
               const float* __restrict__ eb, float* __restrict__ enc,
               float* __restrict__ H)
{
    int n = blockIdx.x * 256 + threadIdx.x;
    int e = blockIdx.y;
    if (n >= NS) return;
    int b  = (n >= TC) ? 1 : 0;
    int tc = n - b * TC;
    float acc = 0.f;
    if (tc < TC) {
        acc = eb[e];
        const float* xb = x + b * TLEN;
        int base = tc * STRIDE_ - FKC;
        #pragma unroll
        for (int k = 0; k < FKC; ++k) {
            int idx = base + k;
            if (idx >= 0 && idx < TLEN) acc += xb[idx] * ew[e * FKC + k];
        }
    }
    enc[(size_t)e * NS + n] = acc;
    H[(size_t)e * NS + n]   = acc;
}

// =====================================================================
// MFMA GEMM (the ONE changed component):
// Out[M][NS] = W[M][KD] * Hin[KD][NS]  (+ fused epilogue), fp32 I/O.
// Inside: LDS bf16 tiles At[m][k], Bt[n][k] (row = 40 shorts, 8-short pad),
// B transposed during staging. 128x128 tile, BK=32, 4 waves (2x2),
// 4x4 frags of mfma_f32_16x16x32_bf16 per wave.
// EPI 0: bias+PReLU+BN | 1: bias | 2: bias+resid
// =====================================================================
#define LROW 40   // shorts per LDS row (32 + 8 pad; 80 B, 16B-aligned frags)

template<int KD, int EPI>
__global__ __launch_bounds__(256)
void gemm_k(const float* __restrict__ W, const float* __restrict__ Hin,
            float* __restrict__ Out, const float* __restrict__ bias,
            const float* __restrict__ alpha, const float* __restrict__ gamma,
            const float* __restrict__ beta,  const float* __restrict__ mean,
            const float* __restrict__ var,   const float* __restrict__ Resid)
{
    __shared__ short At[128 * LROW];   // [m][k]
    __shared__ short Bt[128 * LROW];   // [n][k]

    const int t    = threadIdx.x;
    const int lane = t & 63;
    const int wid  = t >> 6;
    const int wm   = wid >> 1, wn = wid & 1;
    const int r16  = lane & 15, g = lane >> 4;
    const int mb   = blockIdx.y * 128;
    const int nb   = blockIdx.x * 128;

    // staging coords
    const int am = t >> 1;               // 0..127 (A row)
    const int ak = (t & 1) * 16;         // 0 or 16
    const int bn = t & 127;              // 0..127 (B col -> LDS row)
    const int bk = (t >> 7) * 16;        // 0 or 16

    f4v acc[4][4];
    #pragma unroll
    for (int a = 0; a < 4; ++a)
        #pragma unroll
        for (int c = 0; c < 4; ++c)
            acc[a][c] = (f4v){0.f, 0.f, 0.f, 0.f};

    for (int k0 = 0; k0 < KD; k0 += 32) {
        // ---- A: thread loads 16 contiguous fp32 of row (mb+am), converts
        const float4* asrc = (const float4*)&W[(size_t)(mb + am) * KD + k0 + ak];
        float4 a0 = asrc[0], a1 = asrc[1], a2 = asrc[2], a3 = asrc[3];
        // ---- B: 16 coalesced dword loads along n at fixed k, transpose-pack
        float bvals[16];
        #pragma unroll
        for (int kk = 0; kk < 16; ++kk)
            bvals[kk] = Hin[(size_t)(k0 + bk + kk) * NS + nb + bn];

        __syncthreads();   // prior iteration's LDS reads complete
        {
            u4v p;
            p = (u4v){ f2bf(a0.x), f2bf(a0.y), f2bf(a0.z), f2bf(a0.w) };
            *(u4v*)&At[am * LROW + ak + 0]  = p;
            p = (u4v){ f2bf(a1.x), f2bf(a1.y), f2bf(a1.z), f2bf(a1.w) };
            *(u4v*)&At[am * LROW + ak + 4]  = p;
            p = (u4v){ f2bf(a2.x), f2bf(a2.y), f2bf(a2.z), f2bf(a2.w) };
            *(u4v*)&At[am * LROW + ak + 8]  = p;
            p = (u4v){ f2bf(a3.x), f2bf(a3.y), f2bf(a3.z), f2bf(a3.w) };
            *(u4v*)&At[am * LROW + ak + 12] = p;
            #pragma unroll
            for (int q = 0; q < 4; ++q) {
                u4v pb = (u4v){ f2bf(bvals[q*4+0]), f2bf(bvals[q*4+1]),
                                f2bf(bvals[q*4+2]), f2bf(bvals[q*4+3]) };
                *(u4v*)&Bt[bn * LROW + bk + q * 4] = pb;
            }
        }
        __syncthreads();   // tiles ready

        s8v av[4], bv[4];
        #pragma unroll
        for (int f = 0; f < 4; ++f) {
            av[f] = *(const s8v*)&At[(wm * 64 + f * 16 + r16) * LROW + g * 8];
            bv[f] = *(const s8v*)&Bt[(wn * 64 + f * 16 + r16) * LROW + g * 8];
        }
        #pragma unroll
        for (int fm = 0; fm < 4; ++fm)
            #pragma unroll
            for (int fn = 0; fn < 4; ++fn)
                acc[fm][fn] = __builtin_amdgcn_mfma_f32_16x16x32_bf16(
                    av[fm], bv[fn], acc[fm][fn], 0, 0, 0);
    }
    __syncthreads();

    // Epilogue. D frag: col(n) = lane&15, row(m) = (lane>>4)*4 + reg.
    float al = 0.f;
    if constexpr (EPI == 0) al = alpha[0];
    #pragma unroll
    for (int fm = 0; fm < 4; ++fm) {
        #pragma unroll
        for (int r = 0; r < 4; ++r) {
            const int m = mb + wm * 64 + fm * 16 + g * 4 + r;
            float bz = bias[m];
            float sc = 0.f, mn = 0.f, bt = 0.f;
            if constexpr (EPI == 0) {
                sc = gamma[m] / sqrtf(var[m] + EPSV);
                mn = mean[m];
                bt = beta[m];
            }
            float* orow = Out + (size_t)m * NS + nb;
            const float* rrow = (EPI == 2) ? (Resid + (size_t)m * NS + nb) : nullptr;
            #pragma unroll
            for (int fn = 0; fn < 4; ++fn) {
                const int n = wn * 64 + fn * 16 + r16;
                float y = acc[fm][fn][r] + bz;
                if constexpr (EPI == 0) {
                    y = (y > 0.f) ? y : al * y;
                    y = (y - mn) * sc + bt;
                }
                if constexpr (EPI == 2) y += rrow[n];
                orow[n] = y;
            }
        }
    }
}

// =====================================================================
// Depthwise (round-2 verbatim, known-correct)
// =====================================================================
__global__ __launch_bounds__(256)
void dw_k(const float* __restrict__ P, const float* __restrict__ wd,
          const float* __restrict__ bd, const float* __restrict__ a2,
          const float* __restrict__ g2, const float* __restrict__ be2,
          const float* __restrict__ m2, const float* __restrict__ v2,
          float* __restrict__ Q, int dil)
{
    int n = blockIdx.x * 256 + threadIdx.x;
    int d = blockIdx.y;
    if (n >= NS) return;
    int b = (n >= TC) ? 1 : 0;
    int t = n - b * TC;
    const float* row = P + (size_t)d * NS + b * TC;

    float w0 = wd[d * 3 + 0], w1 = wd[d * 3 + 1], w2v = wd[d * 3 + 2];
    float acc = w1 * row[t];
    if (t - dil >= 0) acc += w0 * row[t - dil];
    if (t + dil < TC) acc += w2v * row[t + dil];
    acc += bd[d];
    float al = a2[0];
    acc = (acc > 0.f) ? acc : al * acc;
    float sc = g2[d] / sqrtf(v2[d] + EPSV);
    acc = (acc - m2[d]) * sc + be2[d];
    Q[(size_t)d * NS + n] = acc;
}

// =====================================================================
// mask (round-2 verbatim)
// =====================================================================
__global__ __launch_bounds__(256)
void mask_k(const float* __restrict__ enc, const float* __restrict__ Hf,
            float* __restrict__ masked)
{
    size_t i = (size_t)blockIdx.x * 256 + threadIdx.x;
    if (i >= (size_t)ECH * NS) return;
    float hv = Hf[i];
    float s  = 1.f / (1.f + expf(-hv));
    masked[i] = enc[i] * s;
}

// =====================================================================
// Decoder (round-2 verbatim, known-correct)
// =====================================================================
__global__ __launch_bounds__(256)
void decoder_k(const float* __restrict__ masked, const float* __restrict__ dw,
               const float* __restrict__ db, float* __restrict__ out)
{
    int t0 = blockIdx.x * 256 + threadIdx.x;   // 0..6399
    int b  = blockIdx.y;
    if (t0 >= TLEN / STRIDE_) return;
    int tc0 = t0 + 2;
    float acc[10];
    #pragma unroll
    for (int j = 0; j < 10; ++j) acc[j] = 0.f;

    const float* mcol = masked + (size_t)b * TC + tc0;
    for (int e = 0; e < ECH; ++e) {
        float m0 = mcol[(size_t)e * NS];
        float m1 = mcol[(size_t)e * NS - 1];
        const float* wrow = dw + e * FKC;
        #pragma unroll
        for (int j = 0; j < 10; ++j)
            acc[j] = fmaf(m0, wrow[j], fmaf(m1, wrow[j + 10], acc[j]));
    }
    float bz = db[0];
    float* orow = out + (size_t)b * TLEN + t0 * 10;
    #pragma unroll
    for (int j = 0; j < 10; ++j) orow[j] = acc[j] + bz;
}

// =====================================================================
extern "C" void kernel_launch(void* const* d_in, const int* in_sizes, int n_in,
                              void* d_out, int out_size, void* d_ws, size_t ws_size,
                              hipStream_t stream)
{
    const float* x     = (const float*)d_in[0];
    const float* enc_w = (const float*)d_in[1];
    const float* enc_b = (const float*)d_in[2];
    const float* w1    = (const float*)d_in[3];
    const float* b1    = (const float*)d_in[4];
    const float* a1    = (const float*)d_in[5];
    const float* g1    = (const float*)d_in[6];
    const float* be1   = (const float*)d_in[7];
    const float* m1    = (const float*)d_in[8];
    const float* v1    = (const float*)d_in[9];
    const float* wd    = (const float*)d_in[10];
    const float* bd    = (const float*)d_in[11];
    const float* a2    = (const float*)d_in[12];
    const float* g2    = (const float*)d_in[13];
    const float* be2   = (const float*)d_in[14];
    const float* m2    = (const float*)d_in[15];
    const float* v2    = (const float*)d_in[16];
    const float* w2    = (const float*)d_in[17];
    const float* b2    = (const float*)d_in[18];
    const float* dec_w = (const float*)d_in[19];
    const float* dec_b = (const float*)d_in[20];
    float* out = (float*)d_out;

    float* ws  = (float*)d_ws;
    float* H   = ws;                           // [ECH][NS]
    float* enc = H   + (size_t)ECH * NS;       // [ECH][NS]
    float* R   = enc + (size_t)ECH * NS;       // [ECH][NS]
    float* P   = R   + (size_t)ECH * NS;       // [DCH][NS]
    float* Q   = P   + (size_t)DCH * NS;       // [DCH][NS]

    dim3 blk(256);
    dim3 gEnc((NS + 255) / 256, ECH);
    encoder_k<<<gEnc, blk, 0, stream>>>(x, enc_w, enc_b, enc, H);

    for (int bI = 0; bI < NBLK; ++bI) {
        hipMemcpyAsync(R, H, sizeof(float) * (size_t)ECH * NS,
                       hipMemcpyDeviceToDevice, stream);
        for (int i = 0; i < NLAY; ++i) {
            int li  = bI * NLAY + i;
            int dil = 1 << i;
            // conv1: E->D, fused bias+PReLU+BN
            gemm_k<ECH, 0><<<dim3(NTILE, DCH / 128), blk, 0, stream>>>(
                w1 + (size_t)li * DCH * ECH, H, P,
                b1 + (size_t)li * DCH, a1 + li,
                g1 + (size_t)li * DCH, be1 + (size_t)li * DCH,
                m1 + (size_t)li * DCH, v1 + (size_t)li * DCH, nullptr);
            // depthwise + bias + PReLU + BN
            dim3 gDw((NS + 255) / 256, DCH);
            dw_k<<<gDw, blk, 0, stream>>>(
                P, wd + (size_t)li * DCH * 3, bd + (size_t)li * DCH, a2 + li,
                g2 + (size_t)li * DCH, be2 + (size_t)li * DCH,
                m2 + (size_t)li * DCH, v2 + (size_t)li * DCH, Q, dil);
            // conv2: D->E (+ residual on last layer of block)
            if (i == NLAY - 1) {
                gemm_k<DCH, 2><<<dim3(NTILE, ECH / 128), blk, 0, stream>>>(
                    w2 + (size_t)li * ECH * DCH, Q, H,
                    b2 + (size_t)li * ECH, nullptr, nullptr, nullptr, nullptr,
                    nullptr, R);
            } else {
                gemm_k<DCH, 1><<<dim3(NTILE, ECH / 128), blk, 0, stream>>>(
                    w2 + (size_t)li * ECH * DCH, Q, H,
                    b2 + (size_t)li * ECH, nullptr, nullptr, nullptr, nullptr,
                    nullptr, nullptr);
            }
        }
    }

    // mask + apply (masked into P)
    size_t totE = (size_t)ECH * NS;
    mask_k<<<dim3((unsigned)((totE + 255) / 256)), blk, 0, stream>>>(enc, H, P);

    // decoder
    decoder_k<<<dim3(TLEN / STRIDE_ / 256 + ((TLEN / STRIDE_ % 256) ? 1 : 0), NBLK),
                blk, 0, stream>>>(P, dec_w, dec_b, out);
}

// Round 5
// 781.077 us; speedup vs baseline: 2.4519x; 1.3112x over previous
//
#include <hip/hip_runtime.h>
#include <math.h>

// ---------------- problem constants ----------------
#define TLEN   64000
#define ECH    256
#define DCH    512
#define NBLK   2
#define NLAY   6
#define FKC    20
#define STRIDE_ 10
#define TC     6403            // encoder output length
#define NS     12928           // padded column count = 101*128 (n = b*TC + tc)
#define NTILE  101             // NS / 128
#define EPSV   1e-5f

typedef __attribute__((ext_vector_type(8))) short          s8v;
typedef __attribute__((ext_vector_type(4))) float          f4v;
typedef __attribute__((ext_vector_type(4))) unsigned short u4v;
typedef __attribute__((ext_vector_type(8))) unsigned short u8v;

__device__ __forceinline__ unsigned short f2bf(float f) {
    union { float f; unsigned u; } v; v.f = f;
    unsigned r = v.u + 0x7FFFu + ((v.u >> 16) & 1u);   // RNE
    return (unsigned short)(r >> 16);
}
__device__ __forceinline__ float bf2f(unsigned short h) {
    union { unsigned u; float f; } v; v.u = ((unsigned)h) << 16; return v.f;
}

// =====================================================================
// Encoder (round-4 VERBATIM, verified): fp32 [C][N] enc and H32
// =====================================================================
__global__ __launch_bounds__(256)
void encoder_k(const float* __restrict__ x, const float* __restrict__ ew,
               const float* __restrict__ eb, float* __restrict__ enc,
               float* __restrict__ H)
{
    int n = blockIdx.x * 256 + threadIdx.x;
    int e = blockIdx.y;
    if (n >= NS) return;
    int b  = (n >= TC) ? 1 : 0;
    int tc = n - b * TC;
    float acc = 0.f;
    if (tc < TC) {
        acc = eb[e];
        const float* xb = x + b * TLEN;
        int base = tc * STRIDE_ - FKC;
        #pragma unroll
        for (int k = 0; k < FKC; ++k) {
            int idx = base + k;
            if (idx >= 0 && idx < TLEN) acc += xb[idx] * ew[e * FKC + k];
        }
    }
    enc[(size_t)e * NS + n] = acc;
    H[(size_t)e * NS + n]   = acc;
}

// =====================================================================
// Weight convert fp32 -> bf16 (w1 and w2, each 12*512*256 elems)
// =====================================================================
#define NWQ (12*512*256/4)      // float4 count per tensor = 393216
__global__ __launch_bounds__(256)
void wcvt_k(const float* __restrict__ w1, const float* __restrict__ w2,
            unsigned short* __restrict__ w1b, unsigned short* __restrict__ w2b)
{
    int i = blockIdx.x * 256 + threadIdx.x;
    if (i < NWQ) {
        float4 v = ((const float4*)w1)[i];
        u4v o = { f2bf(v.x), f2bf(v.y), f2bf(v.z), f2bf(v.w) };
        ((u4v*)w1b)[i] = o;
    } else {
        int j = i - NWQ;
        float4 v = ((const float4*)w2)[j];
        u4v o = { f2bf(v.x), f2bf(v.y), f2bf(v.z), f2bf(v.w) };
        ((u4v*)w2b)[j] = o;
    }
}

// =====================================================================
// Transpose-convert: H32 fp32 [ECH][NS] -> Hb bf16 [NS][ECH]
// 64x64 tiles via LDS.
// =====================================================================
__global__ __launch_bounds__(256)
void t2b_k(const float* __restrict__ H32, unsigned short* __restrict__ Hb)
{
    __shared__ float ts[64][65];
    const int t  = threadIdx.x;
    const int n0 = blockIdx.x * 64;
    const int e0 = blockIdx.y * 64;
    const int nl = (t & 15) * 4;
    const int rr = t >> 4;               // 0..15
    #pragma unroll
    for (int r = 0; r < 4; ++r) {
        int er = rr + r * 16;
        float4 v = *(const float4*)&H32[(size_t)(e0 + er) * NS + n0 + nl];
        ts[er][nl + 0] = v.x; ts[er][nl + 1] = v.y;
        ts[er][nl + 2] = v.z; ts[er][nl + 3] = v.w;
    }
    __syncthreads();
    #pragma unroll
    for (int r = 0; r < 4; ++r) {
        int nr = rr + r * 16;
        u4v o = { f2bf(ts[nl + 0][nr]), f2bf(ts[nl + 1][nr]),
                  f2bf(ts[nl + 2][nr]), f2bf(ts[nl + 3][nr]) };
        *(u4v*)&Hb[(size_t)(n0 + nr) * 256 + e0 + nl] = o;
    }
}

// =====================================================================
// bf16 MFMA GEMM, reg-staged (no VALU convert):
//   acc[n][m] = sum_k W[m][k] * Act[n][k]
// W: [MOUT_total rows][KD] bf16; Act: [NS][KD] bf16.
// OUTF 0: write bf16 [NS][MOUT].  OUTF 1: write fp32 [M][NS] (round-4 epi).
// EPI 0: bias+PReLU+BN | 1: bias | 2: bias+resid (Resid bf16 [NS][MOUT])
// 128x128 tile, BK=32, 4 waves (2x2), 4x4 frags mfma_f32_16x16x32_bf16.
// LDS rows padded to 40 shorts.
// =====================================================================
#define LROW 40

template<int KD, int MOUT, int EPI, int OUTF>
__global__ __launch_bounds__(256)
void gemm_bf16_k(const unsigned short* __restrict__ Wb,
                 const unsigned short* __restrict__ Act,
                 unsigned short* __restrict__ OutB,
                 float* __restrict__ OutF,
                 const float* __restrict__ bias,
                 const float* __restrict__ alpha,
                 const float* __restrict__ gamma,
                 const float* __restrict__ beta,
                 const float* __restrict__ mean,
                 const float* __restrict__ var,
                 const unsigned short* __restrict__ Resid)
{
    __shared__ short At[128 * LROW];   // [m][k]
    __shared__ short Bt[128 * LROW];   // [n][k]

    const int t    = threadIdx.x;
    const int lane = t & 63;
    const int wid  = t >> 6;
    const int wm   = wid >> 1, wn = wid & 1;
    const int r16  = lane & 15, g = lane >> 4;
    const int mb   = blockIdx.y * 128;
    const int nb   = blockIdx.x * 128;

    const int arow = t >> 2;            // 0..63
    const int kc8  = (t & 3) * 8;       // short offset within 32-k row

    f4v acc[4][4];
    #pragma unroll
    for (int a = 0; a < 4; ++a)
        #pragma unroll
        for (int c = 0; c < 4; ++c)
            acc[a][c] = (f4v){0.f, 0.f, 0.f, 0.f};

    for (int k0 = 0; k0 < KD; k0 += 32) {
        s8v a0 = *(const s8v*)&Wb[(size_t)(mb + arow)      * KD + k0 + kc8];
        s8v a1 = *(const s8v*)&Wb[(size_t)(mb + arow + 64) * KD + k0 + kc8];
        s8v b0 = *(const s8v*)&Act[(size_t)(nb + arow)      * KD + k0 + kc8];
        s8v b1 = *(const s8v*)&Act[(size_t)(nb + arow + 64) * KD + k0 + kc8];

        __syncthreads();   // prior iteration's frag reads complete
        *(s8v*)&At[(arow)      * LROW + kc8] = a0;
        *(s8v*)&At[(arow + 64) * LROW + kc8] = a1;
        *(s8v*)&Bt[(arow)      * LROW + kc8] = b0;
        *(s8v*)&Bt[(arow + 64) * LROW + kc8] = b1;
        __syncthreads();   // tiles ready

        s8v av[4], bv[4];
        #pragma unroll
        for (int f = 0; f < 4; ++f) {
            av[f] = *(const s8v*)&At[(wm * 64 + f * 16 + r16) * LROW + g * 8];
            bv[f] = *(const s8v*)&Bt[(wn * 64 + f * 16 + r16) * LROW + g * 8];
        }
        #pragma unroll
        for (int fm = 0; fm < 4; ++fm)
            #pragma unroll
            for (int fn = 0; fn < 4; ++fn)
                acc[fm][fn] = __builtin_amdgcn_mfma_f32_16x16x32_bf16(
                    av[fm], bv[fn], acc[fm][fn], 0, 0, 0);
    }

    // Epilogue. D frag: col(n) = lane&15, row(m) = (lane>>4)*4 + reg. (verified)
    float al = 0.f;
    if constexpr (EPI == 0) al = alpha[0];
    #pragma unroll
    for (int fm = 0; fm < 4; ++fm) {
        const int mbase = mb + wm * 64 + fm * 16 + g * 4;
        float4 b4 = *(const float4*)&bias[mbase];
        float bb[4] = { b4.x, b4.y, b4.z, b4.w };
        float sc[4], mn[4], bt[4];
        if constexpr (EPI == 0) {
            float4 g4  = *(const float4*)&gamma[mbase];
            float4 v4  = *(const float4*)&var[mbase];
            float4 m4  = *(const float4*)&mean[mbase];
            float4 be4 = *(const float4*)&beta[mbase];
            sc[0] = g4.x / sqrtf(v4.x + EPSV); sc[1] = g4.y / sqrtf(v4.y + EPSV);
            sc[2] = g4.z / sqrtf(v4.z + EPSV); sc[3] = g4.w / sqrtf(v4.w + EPSV);
            mn[0] = m4.x; mn[1] = m4.y; mn[2] = m4.z; mn[3] = m4.w;
            bt[0] = be4.x; bt[1] = be4.y; bt[2] = be4.z; bt[3] = be4.w;
        }
        #pragma unroll
        for (int fn = 0; fn < 4; ++fn) {
            const int nloc = wn * 64 + fn * 16 + r16;
            const int n    = nb + nloc;
            f4v a = acc[fm][fn];
            u4v rv = {};
            if constexpr (EPI == 2) rv = *(const u4v*)&Resid[(size_t)n * MOUT + mbase];
            float y[4];
            #pragma unroll
            for (int r = 0; r < 4; ++r) {
                float v = a[r] + bb[r];
                if constexpr (EPI == 0) {
                    v = (v > 0.f) ? v : al * v;
                    v = (v - mn[r]) * sc[r] + bt[r];
                }
                if constexpr (EPI == 2) v += bf2f(rv[r]);
                y[r] = v;
            }
            if constexpr (OUTF == 0) {
                u4v ro = { f2bf(y[0]), f2bf(y[1]), f2bf(y[2]), f2bf(y[3]) };
                *(u4v*)&OutB[(size_t)n * MOUT + mbase] = ro;
            } else {
                #pragma unroll
                for (int r = 0; r < 4; ++r)
                    OutF[(size_t)(mbase + r) * NS + n] = y[r];
            }
        }
    }
}

// =====================================================================
// Depthwise K=3 dilated conv + bias + PReLU + BN. bf16 [NS][512].
// Block: 4 n-rows x 64 d-chunks(8).
// =====================================================================
__global__ __launch_bounds__(256)
void dw_k(const unsigned short* __restrict__ P, const float* __restrict__ wd,
          const float* __restrict__ bd, const float* __restrict__ a2,
          const float* __restrict__ g2, const float* __restrict__ be2,
          const float* __restrict__ m2, const float* __restrict__ v2,
          unsigned short* __restrict__ Q, int dil)
{
    const int t  = threadIdx.x;
    const int d8 = (t & 63) * 8;
    const int n  = blockIdx.x * 4 + (t >> 6);
    const int b  = (n >= TC) ? 1 : 0;
    const int tt = n - b * TC;

    u8v c = *(const u8v*)&P[(size_t)n * 512 + d8];
    u8v l = {}, r = {};
    const bool hasL = (tt - dil >= 0);
    const bool hasR = (tt + dil < TC);
    if (hasL) l = *(const u8v*)&P[(size_t)(n - dil) * 512 + d8];
    if (hasR) r = *(const u8v*)&P[(size_t)(n + dil) * 512 + d8];

    float w24[24];
    #pragma unroll
    for (int q = 0; q < 6; ++q) {
        float4 v = *(const float4*)&wd[d8 * 3 + q * 4];
        w24[q*4+0] = v.x; w24[q*4+1] = v.y; w24[q*4+2] = v.z; w24[q*4+3] = v.w;
    }
    float bdv[8], gv[8], bev[8], mnv[8], vrv[8];
    #pragma unroll
    for (int q = 0; q < 2; ++q) {
        float4 v0 = *(const float4*)&bd[d8 + q*4];
        float4 v1 = *(const float4*)&g2[d8 + q*4];
        float4 v2_ = *(const float4*)&be2[d8 + q*4];
        float4 v3 = *(const float4*)&m2[d8 + q*4];
        float4 v4 = *(const float4*)&v2[d8 + q*4];
        bdv[q*4+0]=v0.x; bdv[q*4+1]=v0.y; bdv[q*4+2]=v0.z; bdv[q*4+3]=v0.w;
        gv [q*4+0]=v1.x; gv [q*4+1]=v1.y; gv [q*4+2]=v1.z; gv [q*4+3]=v1.w;
        bev[q*4+0]=v2_.x;bev[q*4+1]=v2_.y;bev[q*4+2]=v2_.z;bev[q*4+3]=v2_.w;
        mnv[q*4+0]=v3.x; mnv[q*4+1]=v3.y; mnv[q*4+2]=v3.z; mnv[q*4+3]=v3.w;
        vrv[q*4+0]=v4.x; vrv[q*4+1]=v4.y; vrv[q*4+2]=v4.z; vrv[q*4+3]=v4.w;
    }
    const float al = a2[0];

    u8v o;
    #pragma unroll
    for (int i = 0; i < 8; ++i) {
        float acc = bf2f(c[i]) * w24[i*3+1];
        if (hasL) acc = fmaf(bf2f(l[i]), w24[i*3+0], acc);
        if (hasR) acc = fmaf(bf2f(r[i]), w24[i*3+2], acc);
        acc += bdv[i];
        acc = (acc > 0.f) ? acc : al * acc;
        acc = (acc - mnv[i]) * (gv[i] / sqrtf(vrv[i] + EPSV)) + bev[i];
        o[i] = f2bf(acc);
    }
    *(u8v*)&Q[(size_t)n * 512 + d8] = o;
}

// =====================================================================
// mask (round-4 VERBATIM): fp32 [C][N]
// =====================================================================
__global__ __launch_bounds__(256)
void mask_k(const float* __restrict__ enc, const float* __restrict__ Hf,
            float* __restrict__ masked)
{
    size_t i = (size_t)blockIdx.x * 256 + threadIdx.x;
    if (i >= (size_t)ECH * NS) return;
    float hv = Hf[i];
    float s  = 1.f / (1.f + expf(-hv));
    masked[i] = enc[i] * s;
}

// =====================================================================
// Decoder (round-4 VERBATIM): fp32 [C][N]
// =====================================================================
__global__ __launch_bounds__(256)
void decoder_k(const float* __restrict__ masked, const float* __restrict__ dw,
               const float* __restrict__ db, float* __restrict__ out)
{
    int t0 = blockIdx.x * 256 + threadIdx.x;   // 0..6399
    int b  = blockIdx.y;
    if (t0 >= TLEN / STRIDE_) return;
    int tc0 = t0 + 2;
    float acc[10];
    #pragma unroll
    for (int j = 0; j < 10; ++j) acc[j] = 0.f;

    const float* mcol = masked + (size_t)b * TC + tc0;
    for (int e = 0; e < ECH; ++e) {
        float m0 = mcol[(size_t)e * NS];
        float m1 = mcol[(size_t)e * NS - 1];
        const float* wrow = dw + e * FKC;
        #pragma unroll
        for (int j = 0; j < 10; ++j)
            acc[j] = fmaf(m0, wrow[j], fmaf(m1, wrow[j + 10], acc[j]));
    }
    float bz = db[0];
    float* orow = out + (size_t)b * TLEN + t0 * 10;
    #pragma unroll
    for (int j = 0; j < 10; ++j) orow[j] = acc[j] + bz;
}

// =====================================================================
extern "C" void kernel_launch(void* const* d_in, const int* in_sizes, int n_in,
                              void* d_out, int out_size, void* d_ws, size_t ws_size,
                              hipStream_t stream)
{
    (void)in_sizes; (void)n_in; (void)out_size; (void)ws_size;
    const float* x     = (const float*)d_in[0];
    const float* enc_w = (const float*)d_in[1];
    const float* enc_b = (const float*)d_in[2];
    const float* w1    = (const float*)d_in[3];
    const float* b1    = (const float*)d_in[4];
    const float* a1    = (const float*)d_in[5];
    const float* g1    = (const float*)d_in[6];
    const float* be1   = (const float*)d_in[7];
    const float* m1    = (const float*)d_in[8];
    const float* v1    = (const float*)d_in[9];
    const float* wd    = (const float*)d_in[10];
    const float* bd    = (const float*)d_in[11];
    const float* a2    = (const float*)d_in[12];
    const float* g2    = (const float*)d_in[13];
    const float* be2   = (const float*)d_in[14];
    const float* m2    = (const float*)d_in[15];
    const float* v2    = (const float*)d_in[16];
    const float* w2    = (const float*)d_in[17];
    const float* b2    = (const float*)d_in[18];
    const float* dec_w = (const float*)d_in[19];
    const float* dec_b = (const float*)d_in[20];
    float* out = (float*)d_out;

    // ---- workspace carve-up ----
    const size_t F_EN = (size_t)ECH * NS * 4;      // 13,238,272 fp32 [C][N]
    const size_t B_EN = (size_t)NS * 256 * 2;      //  6,619,136 bf16 [N][E]
    const size_t B_DN = (size_t)NS * 512 * 2;      // 13,238,272 bf16 [N][D]
    char* p = (char*)d_ws;
    float*          H32   = (float*)p;           p += F_EN;   // enc out / final sep out
    float*          enc32 = (float*)p;           p += F_EN;
    unsigned short* Hb    = (unsigned short*)p;  p += B_EN;
    unsigned short* Rb    = (unsigned short*)p;  p += B_EN;
    unsigned short* Pb    = (unsigned short*)p;  p += B_DN;
    unsigned short* Qb    = (unsigned short*)p;  p += B_DN;
    unsigned short* w1b   = (unsigned short*)p;  p += (size_t)12*512*256*2;
    unsigned short* w2b   = (unsigned short*)p;
    float* masked = (float*)Pb;   // reuse after separator (same byte size)

    dim3 blk(256);
    wcvt_k<<<dim3(2 * NWQ / 256), blk, 0, stream>>>(w1, w2, w1b, w2b);
    encoder_k<<<dim3((NS + 255) / 256, ECH), blk, 0, stream>>>(x, enc_w, enc_b, enc32, H32);
    t2b_k<<<dim3(NS / 64, ECH / 64), blk, 0, stream>>>(H32, Hb);

    for (int bI = 0; bI < NBLK; ++bI) {
        hipMemcpyAsync(Rb, Hb, B_EN, hipMemcpyDeviceToDevice, stream);
        for (int i = 0; i < NLAY; ++i) {
            const int li  = bI * NLAY + i;
            const int dil = 1 << i;
            // conv1: E->D (bias+PReLU+BN), out bf16 [N][D]
            gemm_bf16_k<ECH, DCH, 0, 0><<<dim3(NTILE, 4), blk, 0, stream>>>(
                w1b + (size_t)li * DCH * ECH, Hb, Pb, nullptr,
                b1 + (size_t)li * DCH, a1 + li,
                g1 + (size_t)li * DCH, be1 + (size_t)li * DCH,
                m1 + (size_t)li * DCH, v1 + (size_t)li * DCH, nullptr);
            // depthwise
            dw_k<<<dim3(NS / 4), blk, 0, stream>>>(
                Pb, wd + (size_t)li * DCH * 3, bd + (size_t)li * DCH, a2 + li,
                g2 + (size_t)li * DCH, be2 + (size_t)li * DCH,
                m2 + (size_t)li * DCH, v2 + (size_t)li * DCH, Qb, dil);
            // conv2: D->E
            if (li == NBLK * NLAY - 1) {          // very last: +resid, fp32 [C][N]
                gemm_bf16_k<DCH, ECH, 2, 1><<<dim3(NTILE, 2), blk, 0, stream>>>(
                    w2b + (size_t)li * ECH * DCH, Qb, nullptr, H32,
                    b2 + (size_t)li * ECH, nullptr, nullptr, nullptr,
                    nullptr, nullptr, Rb);
            } else if (i == NLAY - 1) {           // block end: +resid, bf16
                gemm_bf16_k<DCH, ECH, 2, 0><<<dim3(NTILE, 2), blk, 0, stream>>>(
                    w2b + (size_t)li * ECH * DCH, Qb, Hb, nullptr,
                    b2 + (size_t)li * ECH, nullptr, nullptr, nullptr,
                    nullptr, nullptr, Rb);
            } else {
                gemm_bf16_k<DCH, ECH, 1, 0><<<dim3(NTILE, 2), blk, 0, stream>>>(
                    w2b + (size_t)li * ECH * DCH, Qb, Hb, nullptr,
                    b2 + (size_t)li * ECH, nullptr, nullptr, nullptr,
                    nullptr, nullptr, nullptr);
            }
        }
    }

    // mask + apply (fp32 [C][N], round-4 path)
    size_t totE = (size_t)ECH * NS;
    mask_k<<<dim3((unsigned)((totE + 255) / 256)), blk, 0, stream>>>(enc32, H32, masked);
    decoder_k<<<dim3(TLEN / STRIDE_ / 256 + ((TLEN / STRIDE_ % 256) ? 1 : 0), NBLK),
                blk, 0, stream>>>(masked, dec_w, dec_b, out);
}

// Round 9
// 643.718 us; speedup vs baseline: 2.9751x; 1.2134x over previous
//
#include <hip/hip_runtime.h>
#include <math.h>

// ---------------- problem constants ----------------
#define TLEN   64000
#define ECH    256
#define DCH    512
#define NBLK   2
#define NLAY   6
#define FKC    20
#define STRIDE_ 10
#define TC     6403            // encoder output length
#define NS     12928           // padded row count = 101*128 (n = b*TC + tc)
#define NTILE  101             // NS / 128
#define EPSV   1e-5f

typedef __attribute__((ext_vector_type(8))) short          s8v;
typedef __attribute__((ext_vector_type(4))) float          f4v;
typedef __attribute__((ext_vector_type(4))) unsigned short u4v;
typedef __attribute__((ext_vector_type(8))) unsigned short u8v;

__device__ __forceinline__ unsigned short f2bf(float f) {
    union { float f; unsigned u; } v; v.f = f;
    unsigned r = v.u + 0x7FFFu + ((v.u >> 16) & 1u);   // RNE
    return (unsigned short)(r >> 16);
}
__device__ __forceinline__ float bf2f(unsigned short h) {
    union { unsigned u; float f; } v; v.u = ((unsigned)h) << 16; return v.f;
}

// =====================================================================
// Weight convert fp32 -> bf16 (w1 and w2, each 12*512*256 elems)
// =====================================================================
#define NWQ (12*512*256/4)      // float4 count per tensor = 393216
__global__ __launch_bounds__(256)
void wcvt_k(const float* __restrict__ w1, const float* __restrict__ w2,
            unsigned short* __restrict__ w1b, unsigned short* __restrict__ w2b)
{
    int i = blockIdx.x * 256 + threadIdx.x;
    if (i < NWQ) {
        float4 v = ((const float4*)w1)[i];
        u4v o = { f2bf(v.x), f2bf(v.y), f2bf(v.z), f2bf(v.w) };
        ((u4v*)w1b)[i] = o;
    } else {
        int j = i - NWQ;
        float4 v = ((const float4*)w2)[j];
        u4v o = { f2bf(v.x), f2bf(v.y), f2bf(v.z), f2bf(v.w) };
        ((u4v*)w2b)[j] = o;
    }
}

// =====================================================================
// Encoder -> bf16 [N][E] directly (coalesced: lane = e).
// Block: 64 tc x 256 e; x window (660 f32) staged in LDS, broadcast reads.
// Pad rows (n >= 2*TC) left untouched (never consumed by valid outputs;
// 0xAA poison reads as ~-3e-13 bf16, benign through GEMM/dw).
// =====================================================================
__global__ __launch_bounds__(256)
void encoder_k(const float* __restrict__ x, const float* __restrict__ ew,
               const float* __restrict__ eb,
               unsigned short* __restrict__ EncB, unsigned short* __restrict__ Hb)
{
    __shared__ float xs[660];
    const int bx  = blockIdx.x;      // 0..100
    const int b   = blockIdx.y;      // 0..1
    const int tc0 = bx * 64;
    const int base_g = tc0 * STRIDE_ - FKC;
    for (int i = threadIdx.x; i < 660; i += 256) {
        int idx = base_g + i;
        xs[i] = (idx >= 0 && idx < TLEN) ? x[b * TLEN + idx] : 0.f;
    }
    __syncthreads();

    const int e = threadIdx.x;
    float w[20];
    #pragma unroll
    for (int q = 0; q < 5; ++q) {
        float4 v = *(const float4*)&ew[e * 20 + q * 4];
        w[q*4+0] = v.x; w[q*4+1] = v.y; w[q*4+2] = v.z; w[q*4+3] = v.w;
    }
    const float bz = eb[e];
    const int jmax = (TC - tc0 < 64) ? (TC - tc0) : 64;
    for (int j = 0; j < jmax; ++j) {
        const float* xp = &xs[j * 10];
        float acc = bz;
        #pragma unroll
        for (int k = 0; k < 20; ++k) acc = fmaf(xp[k], w[k], acc);
        unsigned short hv = f2bf(acc);
        size_t o = (size_t)(b * TC + tc0 + j) * 256 + e;
        EncB[o] = hv;
        Hb[o]   = hv;
    }
}

// =====================================================================
// bf16 MFMA GEMM, reg-staged with one-step register PREFETCH:
//   acc[n][m] = sum_k W[m][k] * Act[n][k];  Out bf16 [NS][MOUT]
// EPI 0: bias+PReLU+BN | 1: bias | 2: bias+resid (in-place Out==Resid safe:
//        each cell read+written only by its own thread; Act is a different
//        buffer)
// 128x128 tile, BK=32, 4 waves (2x2), 4x4 frags mfma_f32_16x16x32_bf16.
// =====================================================================
#define LROW 40

template<int KD, int MOUT, int EPI>
__global__ __launch_bounds__(256)
void gemm_bf16_k(const unsigned short* __restrict__ Wb,
                 const unsigned short* __restrict__ Act,
                 unsigned short* __restrict__ OutB,
                 const float* __restrict__ bias,
                 const float* __restrict__ alpha,
                 const float* __restrict__ gamma,
                 const float* __restrict__ beta,
                 const float* __restrict__ mean,
                 const float* __restrict__ var,
                 const unsigned short* __restrict__ Resid)
{
    __shared__ short At[128 * LROW];   // [m][k]
    __shared__ short Bt[128 * LROW];   // [n][k]

    const int t    = threadIdx.x;
    const int lane = t & 63;
    const int wid  = t >> 6;
    const int wm   = wid >> 1, wn = wid & 1;
    const int r16  = lane & 15, g = lane >> 4;
    const int mb   = blockIdx.y * 128;
    const int nb   = blockIdx.x * 128;

    const int arow = t >> 2;            // 0..63
    const int kc8  = (t & 3) * 8;       // short offset within 32-k row

    const unsigned short* pA0 = &Wb[(size_t)(mb + arow)      * KD + kc8];
    const unsigned short* pA1 = &Wb[(size_t)(mb + arow + 64) * KD + kc8];
    const unsigned short* pB0 = &Act[(size_t)(nb + arow)      * KD + kc8];
    const unsigned short* pB1 = &Act[(size_t)(nb + arow + 64) * KD + kc8];

    f4v acc[4][4];
    #pragma unroll
    for (int a = 0; a < 4; ++a)
        #pragma unroll
        for (int c = 0; c < 4; ++c)
            acc[a][c] = (f4v){0.f, 0.f, 0.f, 0.f};

    constexpr int NSTEP = KD / 32;
    s8v a0 = *(const s8v*)(pA0);
    s8v a1 = *(const s8v*)(pA1);
    s8v b0 = *(const s8v*)(pB0);
    s8v b1 = *(const s8v*)(pB1);

    for (int s = 0; s < NSTEP; ++s) {
        __syncthreads();   // prior iteration's frag reads complete
        *(s8v*)&At[(arow)      * LROW + kc8] = a0;
        *(s8v*)&At[(arow + 64) * LROW + kc8] = a1;
        *(s8v*)&Bt[(arow)      * LROW + kc8] = b0;
        *(s8v*)&Bt[(arow + 64) * LROW + kc8] = b1;
        __syncthreads();   // tiles ready

        const int k0n = ((s + 1 < NSTEP) ? (s + 1) : s) * 32;
        s8v na0 = *(const s8v*)(pA0 + k0n);
        s8v na1 = *(const s8v*)(pA1 + k0n);
        s8v nb0 = *(const s8v*)(pB0 + k0n);
        s8v nb1 = *(const s8v*)(pB1 + k0n);

        s8v av[4], bv[4];
        #pragma unroll
        for (int f = 0; f < 4; ++f) {
            av[f] = *(const s8v*)&At[(wm * 64 + f * 16 + r16) * LROW + g * 8];
            bv[f] = *(const s8v*)&Bt[(wn * 64 + f * 16 + r16) * LROW + g * 8];
        }
        #pragma unroll
        for (int fm = 0; fm < 4; ++fm)
            #pragma unroll
            for (int fn = 0; fn < 4; ++fn)
                acc[fm][fn] = __builtin_amdgcn_mfma_f32_16x16x32_bf16(
                    av[fm], bv[fn], acc[fm][fn], 0, 0, 0);

        a0 = na0; a1 = na1; b0 = nb0; b1 = nb1;
    }

    // Epilogue. D frag: col(n) = lane&15, row(m) = (lane>>4)*4 + reg. (verified)
    float al = 0.f;
    if constexpr (EPI == 0) al = alpha[0];
    #pragma unroll
    for (int fm = 0; fm < 4; ++fm) {
        const int mbase = mb + wm * 64 + fm * 16 + g * 4;
        float4 b4 = *(const float4*)&bias[mbase];
        float bb[4] = { b4.x, b4.y, b4.z, b4.w };
        float sc[4], mn[4], bt[4];
        if constexpr (EPI == 0) {
            float4 g4  = *(const float4*)&gamma[mbase];
            float4 v4  = *(const float4*)&var[mbase];
            float4 m4  = *(const float4*)&mean[mbase];
            float4 be4 = *(const float4*)&beta[mbase];
            sc[0] = g4.x / sqrtf(v4.x + EPSV); sc[1] = g4.y / sqrtf(v4.y + EPSV);
            sc[2] = g4.z / sqrtf(v4.z + EPSV); sc[3] = g4.w / sqrtf(v4.w + EPSV);
            mn[0] = m4.x; mn[1] = m4.y; mn[2] = m4.z; mn[3] = m4.w;
            bt[0] = be4.x; bt[1] = be4.y; bt[2] = be4.z; bt[3] = be4.w;
        }
        #pragma unroll
        for (int fn = 0; fn < 4; ++fn) {
            const int n = nb + wn * 64 + fn * 16 + r16;
            f4v a = acc[fm][fn];
            u4v rv = {};
            if constexpr (EPI == 2) rv = *(const u4v*)&Resid[(size_t)n * MOUT + mbase];
            u4v ro;
            #pragma unroll
            for (int r = 0; r < 4; ++r) {
                float v = a[r] + bb[r];
                if constexpr (EPI == 0) {
                    v = (v > 0.f) ? v : al * v;
                    v = (v - mn[r]) * sc[r] + bt[r];
                }
                if constexpr (EPI == 2) v += bf2f(rv[r]);
                ro[r] = f2bf(v);
            }
            *(u4v*)&OutB[(size_t)n * MOUT + mbase] = ro;
        }
    }
}

// =====================================================================
// Depthwise K=3 dilated conv + bias + PReLU + BN. bf16 [NS][512].
// (verified)
// =====================================================================
__global__ __launch_bounds__(256)
void dw_k(const unsigned short* __restrict__ P, const float* __restrict__ wd,
          const float* __restrict__ bd, const float* __restrict__ a2,
          const float* __restrict__ g2, const float* __restrict__ be2,
          const float* __restrict__ m2, const float* __restrict__ v2,
          unsigned short* __restrict__ Q, int dil)
{
    const int t  = threadIdx.x;
    const int d8 = (t & 63) * 8;
    const int n  = blockIdx.x * 4 + (t >> 6);
    const int b  = (n >= TC) ? 1 : 0;
    const int tt = n - b * TC;

    u8v c = *(const u8v*)&P[(size_t)n * 512 + d8];
    u8v l = {}, r = {};
    const bool hasL = (tt - dil >= 0);
    const bool hasR = (tt + dil < TC);
    if (hasL) l = *(const u8v*)&P[(size_t)(n - dil) * 512 + d8];
    if (hasR) r = *(const u8v*)&P[(size_t)(n + dil) * 512 + d8];

    float w24[24];
    #pragma unroll
    for (int q = 0; q < 6; ++q) {
        float4 v = *(const float4*)&wd[d8 * 3 + q * 4];
        w24[q*4+0] = v.x; w24[q*4+1] = v.y; w24[q*4+2] = v.z; w24[q*4+3] = v.w;
    }
    float bdv[8], gv[8], bev[8], mnv[8], vrv[8];
    #pragma unroll
    for (int q = 0; q < 2; ++q) {
        float4 v0 = *(const float4*)&bd[d8 + q*4];
        float4 v1 = *(const float4*)&g2[d8 + q*4];
        float4 v2_ = *(const float4*)&be2[d8 + q*4];
        float4 v3 = *(const float4*)&m2[d8 + q*4];
        float4 v4 = *(const float4*)&v2[d8 + q*4];
        bdv[q*4+0]=v0.x; bdv[q*4+1]=v0.y; bdv[q*4+2]=v0.z; bdv[q*4+3]=v0.w;
        gv [q*4+0]=v1.x; gv [q*4+1]=v1.y; gv [q*4+2]=v1.z; gv [q*4+3]=v1.w;
        bev[q*4+0]=v2_.x;bev[q*4+1]=v2_.y;bev[q*4+2]=v2_.z;bev[q*4+3]=v2_.w;
        mnv[q*4+0]=v3.x; mnv[q*4+1]=v3.y; mnv[q*4+2]=v3.z; mnv[q*4+3]=v3.w;
        vrv[q*4+0]=v4.x; vrv[q*4+1]=v4.y; vrv[q*4+2]=v4.z; vrv[q*4+3]=v4.w;
    }
    const float al = a2[0];

    u8v o;
    #pragma unroll
    for (int i = 0; i < 8; ++i) {
        float acc = bf2f(c[i]) * w24[i*3+1];
        if (hasL) acc = fmaf(bf2f(l[i]), w24[i*3+0], acc);
        if (hasR) acc = fmaf(bf2f(r[i]), w24[i*3+2], acc);
        acc += bdv[i];
        acc = (acc > 0.f) ? acc : al * acc;
        acc = (acc - mnv[i]) * (gv[i] / sqrtf(vrv[i] + EPSV)) + bev[i];
        o[i] = f2bf(acc);
    }
    *(u8v*)&Q[(size_t)n * 512 + d8] = o;
}

// =====================================================================
// mask: masked = enc * sigmoid(H), bf16 [N][E], x8 vectorized
// =====================================================================
#define TOT8 ((ECH * NS) / 8)    // 413696
__global__ __launch_bounds__(256)
void mask_k(const unsigned short* __restrict__ EncB,
            const unsigned short* __restrict__ Hb,
            unsigned short* __restrict__ Mb)
{
    int i = blockIdx.x * 256 + threadIdx.x;
    u8v ev = ((const u8v*)EncB)[i];
    u8v hv = ((const u8v*)Hb)[i];
    u8v o;
    #pragma unroll
    for (int k = 0; k < 8; ++k) {
        float h = bf2f(hv[k]);
        float s = 1.f / (1.f + expf(-h));
        o[k] = f2bf(bf2f(ev[k]) * s);
    }
    ((u8v*)Mb)[i] = o;
}

// =====================================================================
// Decoder on bf16 [N][E]:
// out[b][10*t0+j] = db + sum_e M[t0+2][e]*dw[e][j] + M[t0+1][e]*dw[e][j+10]
// Block: 32 t0 x 8 e-groups (32 e each); LDS weight stage + LDS reduce.
// FIX (r8 post-mortem): reduce loop covers all 320 slots with 256 threads
// (was `if (t < 320)` -> slots 256..319 never written -> zeros in output).
// =====================================================================
__global__ __launch_bounds__(256)
void decoder_k(const unsigned short* __restrict__ Mb,
               const float* __restrict__ dec_w, const float* __restrict__ db,
               float* __restrict__ out)
{
    __shared__ float wlds[5120];        // [256 e][20 k]
    __shared__ float red[2560];         // [32 t0][8 grp][10 j]
    const int t = threadIdx.x;
    #pragma unroll
    for (int i = 0; i < 5; ++i)
        ((float4*)wlds)[t + i * 256] = ((const float4*)dec_w)[t + i * 256];
    __syncthreads();

    const int grp = t >> 5;             // 0..7
    const int t0l = t & 31;
    const int t0  = blockIdx.x * 32 + t0l;
    const int by  = blockIdx.y;
    const int n0  = by * TC + t0 + 2;
    const int e0  = grp * 32;

    float acc[10];
    #pragma unroll
    for (int j = 0; j < 10; ++j) acc[j] = 0.f;

    #pragma unroll
    for (int q = 0; q < 4; ++q) {
        u8v a0 = *(const u8v*)&Mb[(size_t)n0 * 256 + e0 + q * 8];
        u8v a1 = *(const u8v*)&Mb[(size_t)(n0 - 1) * 256 + e0 + q * 8];
        #pragma unroll
        for (int i = 0; i < 8; ++i) {
            float m0 = bf2f(a0[i]);
            float m1 = bf2f(a1[i]);
            const float* wr = &wlds[(e0 + q * 8 + i) * 20];
            #pragma unroll
            for (int j = 0; j < 10; ++j)
                acc[j] = fmaf(m0, wr[j], fmaf(m1, wr[j + 10], acc[j]));
        }
    }
    #pragma unroll
    for (int j = 0; j < 10; ++j)
        red[(t0l * 8 + grp) * 10 + j] = acc[j];
    __syncthreads();

    for (int s = t; s < 320; s += 256) {          // FIXED coverage
        int t0l2 = s / 10, j = s - t0l2 * 10;
        float sm = 0.f;
        #pragma unroll
        for (int gq = 0; gq < 8; ++gq) sm += red[(t0l2 * 8 + gq) * 10 + j];
        out[(size_t)by * TLEN + (size_t)(blockIdx.x * 32 + t0l2) * 10 + j] = sm + db[0];
    }
}

// =====================================================================
extern "C" void kernel_launch(void* const* d_in, const int* in_sizes, int n_in,
                              void* d_out, int out_size, void* d_ws, size_t ws_size,
                              hipStream_t stream)
{
    (void)in_sizes; (void)n_in; (void)out_size; (void)ws_size;
    const float* x     = (const float*)d_in[0];
    const float* enc_w = (const float*)d_in[1];
    const float* enc_b = (const float*)d_in[2];
    const float* w1    = (const float*)d_in[3];
    const float* b1    = (const float*)d_in[4];
    const float* a1    = (const float*)d_in[5];
    const float* g1    = (const float*)d_in[6];
    const float* be1   = (const float*)d_in[7];
    const float* m1    = (const float*)d_in[8];
    const float* v1    = (const float*)d_in[9];
    const float* wd    = (const float*)d_in[10];
    const float* bd    = (const float*)d_in[11];
    const float* a2    = (const float*)d_in[12];
    const float* g2    = (const float*)d_in[13];
    const float* be2   = (const float*)d_in[14];
    const float* m2    = (const float*)d_in[15];
    const float* v2    = (const float*)d_in[16];
    const float* w2    = (const float*)d_in[17];
    const float* b2    = (const float*)d_in[18];
    const float* dec_w = (const float*)d_in[19];
    const float* dec_b = (const float*)d_in[20];
    float* out = (float*)d_out;

    // ---- workspace carve-up (all bf16 activations, [N][C] layouts) ----
    const size_t B_EN = (size_t)NS * 256 * 2;      //  6,619,136
    const size_t B_DN = (size_t)NS * 512 * 2;      // 13,238,272
    char* p = (char*)d_ws;
    unsigned short* Hb   = (unsigned short*)p;  p += B_EN;   // block input / residual
    unsigned short* Hb2  = (unsigned short*)p;  p += B_EN;   // intra-block H
    unsigned short* EncB = (unsigned short*)p;  p += B_EN;
    unsigned short* Pb   = (unsigned short*)p;  p += B_DN;
    unsigned short* Qb   = (unsigned short*)p;  p += B_DN;
    unsigned short* w1b  = (unsigned short*)p;  p += (size_t)12*512*256*2;
    unsigned short* w2b  = (unsigned short*)p;
    unsigned short* Mb   = Pb;   // reuse after separator

    dim3 blk(256);
    wcvt_k<<<dim3(2 * NWQ / 256), blk, 0, stream>>>(w1, w2, w1b, w2b);
    encoder_k<<<dim3(101, 2), blk, 0, stream>>>(x, enc_w, enc_b, EncB, Hb);

    for (int bI = 0; bI < NBLK; ++bI) {
        for (int i = 0; i < NLAY; ++i) {
            const int li  = bI * NLAY + i;
            const int dil = 1 << i;
            // conv1: E->D (bias+PReLU+BN); layer0 reads block input Hb, else Hb2
            const unsigned short* hin = (i == 0) ? Hb : Hb2;
            gemm_bf16_k<ECH, DCH, 0><<<dim3(NTILE, 4), blk, 0, stream>>>(
                w1b + (size_t)li * DCH * ECH, hin, Pb,
                b1 + (size_t)li * DCH, a1 + li,
                g1 + (size_t)li * DCH, be1 + (size_t)li * DCH,
                m1 + (size_t)li * DCH, v1 + (size_t)li * DCH, nullptr);
            // depthwise
            dw_k<<<dim3(NS / 4), blk, 0, stream>>>(
                Pb, wd + (size_t)li * DCH * 3, bd + (size_t)li * DCH, a2 + li,
                g2 + (size_t)li * DCH, be2 + (size_t)li * DCH,
                m2 + (size_t)li * DCH, v2 + (size_t)li * DCH, Qb, dil);
            // conv2: D->E; block-end adds residual (Hb) and writes Hb in-place
            if (i == NLAY - 1) {
                gemm_bf16_k<DCH, ECH, 2><<<dim3(NTILE, 2), blk, 0, stream>>>(
                    w2b + (size_t)li * ECH * DCH, Qb, Hb,
                    b2 + (size_t)li * ECH, nullptr, nullptr, nullptr,
                    nullptr, nullptr, Hb);
            } else {
                gemm_bf16_k<DCH, ECH, 1><<<dim3(NTILE, 2), blk, 0, stream>>>(
                    w2b + (size_t)li * ECH * DCH, Qb, Hb2,
                    b2 + (size_t)li * ECH, nullptr, nullptr, nullptr,
                    nullptr, nullptr, nullptr);
            }
        }
    }

    mask_k<<<dim3(TOT8 / 256), blk, 0, stream>>>(EncB, Hb, Mb);
    decoder_k<<<dim3(200, 2), blk, 0, stream>>>(Mb, dec_w, dec_b, out);
}